// Round 1
// baseline (6918.391 us; speedup 1.0000x reference)
//
#include <hip/hip_runtime.h>
#include <hip/hip_bf16.h>

// ---------------------------------------------------------------------------
// HeteroTextGCN: 2-layer hetero GraphConv (norm='both', sum aggregate) + FC.
// Pipeline:
//   1. degree histograms (int atomics) -> s_out/s_in = rsqrt(max(deg,1))
//   2. per relation r: h_r = (x * s_out_r) @ W0[r]   (fp32 register-tiled GEMM)
//                      atomic-scatter h_r[src]*s_in_r[dst] into acc0[dst]
//   3. acc0 = leakyrelu(acc0 + sum_r b0[r])
//   4. per relation r: same with W1[r], scatter into d_out h-region
//   5. h += sum_r b1[r];  logits = h @ fc_W + fc_b
// ---------------------------------------------------------------------------

#define BM 128
#define BN 128
#define BK 32
#define TM 8
#define TN 8

__global__ __launch_bounds__(256)
void hist_kernel(const int* __restrict__ src, const int* __restrict__ dst,
                 int* __restrict__ cnt_out, int* __restrict__ cnt_in,
                 int total, int E, int N) {
    int i = blockIdx.x * blockDim.x + threadIdx.x;
    if (i >= total) return;
    int r = i / E;
    atomicAdd(cnt_out + (size_t)r * N + src[i], 1);
    atomicAdd(cnt_in  + (size_t)r * N + dst[i], 1);
}

__global__ __launch_bounds__(256)
void scales_kernel(const int* __restrict__ cnt_out, const int* __restrict__ cnt_in,
                   float* __restrict__ s_out, float* __restrict__ s_in, int total) {
    int i = blockIdx.x * blockDim.x + threadIdx.x;
    if (i >= total) return;
    s_out[i] = rsqrtf(fmaxf((float)cnt_out[i], 1.0f));
    s_in[i]  = rsqrtf(fmaxf((float)cnt_in[i],  1.0f));
}

// C[M x 128] = (A[M x K] row-scaled by scale[M]) @ B[K x 128]
__global__ __launch_bounds__(256, 2)
void gemm_rowscale(const float* __restrict__ A, const float* __restrict__ scale,
                   const float* __restrict__ B, float* __restrict__ C,
                   int M, int K) {
    __shared__ float As[BK][BM];   // transposed tile: As[k][m]
    __shared__ float Bs[BK][BN];

    const int tid = threadIdx.x;
    const int m0  = blockIdx.x * BM;
    const int tm  = tid >> 4;          // 0..15 -> row group
    const int tn  = tid & 15;          // 0..15 -> col group

    float acc[TM][TN];
#pragma unroll
    for (int i = 0; i < TM; i++)
#pragma unroll
        for (int j = 0; j < TN; j++) acc[i][j] = 0.0f;

    const int a_row = tid >> 3;          // 0..31 (+32*i -> 128 rows)
    const int a_k4  = (tid & 7) * 4;     // k offset within BK
    const int b_row = tid >> 5;          // 0..7  (+8*i -> 32 rows)
    const int b_c4  = (tid & 31) * 4;    // col offset

    for (int k0 = 0; k0 < K; k0 += BK) {
#pragma unroll
        for (int i = 0; i < 4; i++) {
            int mm = a_row + i * 32;
            int m  = m0 + mm;
            float4 v = make_float4(0.f, 0.f, 0.f, 0.f);
            float  s = 0.f;
            if (m < M) {
                v = *(const float4*)(A + (size_t)m * K + k0 + a_k4);
                s = scale[m];
            }
            As[a_k4 + 0][mm] = v.x * s;
            As[a_k4 + 1][mm] = v.y * s;
            As[a_k4 + 2][mm] = v.z * s;
            As[a_k4 + 3][mm] = v.w * s;
        }
#pragma unroll
        for (int i = 0; i < 4; i++) {
            int kk = b_row + i * 8;
            *(float4*)(&Bs[kk][b_c4]) = *(const float4*)(B + (size_t)(k0 + kk) * BN + b_c4);
        }
        __syncthreads();

#pragma unroll
        for (int k = 0; k < BK; k++) {
            float a[TM], b[TN];
            *(float4*)&a[0] = *(const float4*)&As[k][tm * TM];
            *(float4*)&a[4] = *(const float4*)&As[k][tm * TM + 4];
            *(float4*)&b[0] = *(const float4*)&Bs[k][tn * TN];
            *(float4*)&b[4] = *(const float4*)&Bs[k][tn * TN + 4];
#pragma unroll
            for (int i = 0; i < TM; i++)
#pragma unroll
                for (int j = 0; j < TN; j++)
                    acc[i][j] = fmaf(a[i], b[j], acc[i][j]);
        }
        __syncthreads();
    }

#pragma unroll
    for (int i = 0; i < TM; i++) {
        int m = m0 + tm * TM + i;
        if (m < M) {
            *(float4*)(C + (size_t)m * BN + tn * TN)     = *(float4*)&acc[i][0];
            *(float4*)(C + (size_t)m * BN + tn * TN + 4) = *(float4*)&acc[i][4];
        }
    }
}

// acc[dst[e]][c] += h[src[e]][c] * s_in[dst[e]]  (128 channels, 4/thread)
__global__ __launch_bounds__(256)
void scatter_add(const float* __restrict__ h, const int* __restrict__ src,
                 const int* __restrict__ dst, const float* __restrict__ s_in,
                 float* __restrict__ acc, int n_edges) {
    int idx = blockIdx.x * blockDim.x + threadIdx.x;
    int e = idx >> 5;
    int g = idx & 31;
    if (e >= n_edges) return;
    int s = src[e], d = dst[e];
    float w = s_in[d];
    float4 v = *(const float4*)(h + (size_t)s * 128 + g * 4);
    float* p = acc + (size_t)d * 128 + g * 4;
    atomicAdd(p + 0, v.x * w);
    atomicAdd(p + 1, v.y * w);
    atomicAdd(p + 2, v.z * w);
    atomicAdd(p + 3, v.w * w);
}

// h = leakyrelu(h + sum_r b[r]) elementwise (float4 over N*128)
__global__ __launch_bounds__(256)
void bias_act_kernel(float* __restrict__ h, const float* __restrict__ b, int total4) {
    int i = blockIdx.x * blockDim.x + threadIdx.x;
    if (i >= total4) return;
    int g = (i & 31) * 4;
    float4 v = *(float4*)(h + (size_t)i * 4);
    float4 b0v = *(const float4*)(b + g);
    float4 b1v = *(const float4*)(b + 128 + g);
    float4 b2v = *(const float4*)(b + 256 + g);
    v.x += b0v.x + b1v.x + b2v.x;
    v.y += b0v.y + b1v.y + b2v.y;
    v.z += b0v.z + b1v.z + b2v.z;
    v.w += b0v.w + b1v.w + b2v.w;
    v.x = fmaxf(v.x, 0.f) + 0.01f * fminf(v.x, 0.f);
    v.y = fmaxf(v.y, 0.f) + 0.01f * fminf(v.y, 0.f);
    v.z = fmaxf(v.z, 0.f) + 0.01f * fminf(v.z, 0.f);
    v.w = fmaxf(v.w, 0.f) + 0.01f * fminf(v.w, 0.f);
    *(float4*)(h + (size_t)i * 4) = v;
}

// h += sum_r b[r] (no activation)
__global__ __launch_bounds__(256)
void bias_only_kernel(float* __restrict__ h, const float* __restrict__ b, int total4) {
    int i = blockIdx.x * blockDim.x + threadIdx.x;
    if (i >= total4) return;
    int g = (i & 31) * 4;
    float4 v = *(float4*)(h + (size_t)i * 4);
    float4 b0v = *(const float4*)(b + g);
    float4 b1v = *(const float4*)(b + 128 + g);
    float4 b2v = *(const float4*)(b + 256 + g);
    v.x += b0v.x + b1v.x + b2v.x;
    v.y += b0v.y + b1v.y + b2v.y;
    v.z += b0v.z + b1v.z + b2v.z;
    v.w += b0v.w + b1v.w + b2v.w;
    *(float4*)(h + (size_t)i * 4) = v;
}

// logits[n][j] = fc_b[j] + sum_c h[n][c] * fc_W[c][j]   (thread per (n,j))
__global__ __launch_bounds__(256)
void logits_kernel(const float* __restrict__ h, const float* __restrict__ fcW,
                   const float* __restrict__ fcb, float* __restrict__ out, int N) {
    int i = blockIdx.x * blockDim.x + threadIdx.x;
    if (i >= N * 16) return;
    int n = i >> 4, j = i & 15;
    float acc = fcb[j];
    const float* hr = h + (size_t)n * 128;
#pragma unroll
    for (int c = 0; c < 128; c++) acc = fmaf(hr[c], fcW[c * 16 + j], acc);
    out[(size_t)n * 16 + j] = acc;
}

extern "C" void kernel_launch(void* const* d_in, const int* in_sizes, int n_in,
                              void* d_out, int out_size, void* d_ws, size_t ws_size,
                              hipStream_t stream) {
    const float* x   = (const float*)d_in[0];
    const int*   src = (const int*)d_in[1];
    const int*   dst = (const int*)d_in[2];
    const float* W0  = (const float*)d_in[3];
    const float* b0  = (const float*)d_in[4];
    const float* W1  = (const float*)d_in[5];
    const float* b1  = (const float*)d_in[6];
    const float* fcW = (const float*)d_in[7];
    const float* fcb = (const float*)d_in[8];

    const int N = in_sizes[0] / 256;   // 100000
    const int E = in_sizes[1] / 3;     // 600000

    float* out_h      = (float*)d_out;                    // N*128
    float* out_logits = out_h + (size_t)N * 128;          // N*16

    // workspace layout
    float* s_out   = (float*)d_ws;                        // 3N
    float* s_in    = s_out + 3 * (size_t)N;               // 3N
    int*   cnt_out = (int*)(s_in + 3 * (size_t)N);        // 3N
    int*   cnt_in  = cnt_out + 3 * (size_t)N;             // 3N
    float* hbuf    = (float*)(cnt_in + 3 * (size_t)N);    // N*128
    float* acc0    = hbuf + (size_t)N * 128;              // N*128

    hipMemsetAsync(cnt_out, 0, 2 * 3 * (size_t)N * sizeof(int), stream);
    hipMemsetAsync(acc0, 0, (size_t)N * 128 * sizeof(float), stream);
    hipMemsetAsync(d_out, 0, (size_t)out_size * sizeof(float), stream);

    {
        int total = 3 * E;
        hist_kernel<<<(total + 255) / 256, 256, 0, stream>>>(src, dst, cnt_out, cnt_in, total, E, N);
    }
    {
        int total = 3 * N;
        scales_kernel<<<(total + 255) / 256, 256, 0, stream>>>(cnt_out, cnt_in, s_out, s_in, total);
    }

    int gemm_blocks = (N + BM - 1) / BM;
    int scat_blocks = (E * 32 + 255) / 256;

    // Layer 0: x[N,256] -> acc0[N,128]
    for (int r = 0; r < 3; r++) {
        gemm_rowscale<<<gemm_blocks, 256, 0, stream>>>(
            x, s_out + (size_t)r * N, W0 + (size_t)r * 256 * 128, hbuf, N, 256);
        scatter_add<<<scat_blocks, 256, 0, stream>>>(
            hbuf, src + (size_t)r * E, dst + (size_t)r * E, s_in + (size_t)r * N, acc0, E);
    }
    bias_act_kernel<<<(N * 32 + 255) / 256, 256, 0, stream>>>(acc0, b0, N * 32);

    // Layer 1: acc0[N,128] -> out_h[N,128]
    for (int r = 0; r < 3; r++) {
        gemm_rowscale<<<gemm_blocks, 256, 0, stream>>>(
            acc0, s_out + (size_t)r * N, W1 + (size_t)r * 128 * 128, hbuf, N, 128);
        scatter_add<<<scat_blocks, 256, 0, stream>>>(
            hbuf, src + (size_t)r * E, dst + (size_t)r * E, s_in + (size_t)r * N, out_h, E);
    }
    bias_only_kernel<<<(N * 32 + 255) / 256, 256, 0, stream>>>(out_h, b1, N * 32);

    // logits = h @ fc_W + fc_b
    logits_kernel<<<(N * 16 + 255) / 256, 256, 0, stream>>>(out_h, fcW, fcb, out_logits, N);
}

// Round 2
// 1489.375 us; speedup vs baseline: 4.6452x; 4.6452x over previous
//
#include <hip/hip_runtime.h>
#include <hip/hip_bf16.h>

// ---------------------------------------------------------------------------
// HeteroTextGCN: 2-layer hetero GraphConv (norm='both', sum aggregate) + FC.
// Round 1: replace 461M float atomics (88% of runtime) with per-call CSR
// build (int atomics only) + wave-per-dst-node register gather.
// ---------------------------------------------------------------------------

#define BM 128
#define BN 128
#define BK 32
#define TM 8
#define TN 8

#define SCAN_T 256
#define SCAN_E 8
#define SCAN_BLK (SCAN_T * SCAN_E)   // 2048 elements per scan block

__global__ __launch_bounds__(256)
void hist_kernel(const int* __restrict__ src, const int* __restrict__ dst,
                 int* __restrict__ cnt_out, int* __restrict__ cnt_in,
                 int E, int N) {
    int e = blockIdx.x * blockDim.x + threadIdx.x;
    int r = blockIdx.y;
    if (e >= E) return;
    atomicAdd(cnt_out + (size_t)r * N + src[(size_t)r * E + e], 1);
    atomicAdd(cnt_in  + (size_t)r * N + dst[(size_t)r * E + e], 1);
}

__global__ __launch_bounds__(256)
void scales_kernel(const int* __restrict__ cnt_out, const int* __restrict__ cnt_in,
                   float* __restrict__ s_out, float* __restrict__ s_in, int total) {
    int i = blockIdx.x * blockDim.x + threadIdx.x;
    if (i >= total) return;
    s_out[i] = rsqrtf(fmaxf((float)cnt_out[i], 1.0f));
    s_in[i]  = rsqrtf(fmaxf((float)cnt_in[i],  1.0f));
}

// --- 3-pass exclusive scan of cnt_in per relation -> row_start[r][0..N] ----
__global__ __launch_bounds__(SCAN_T)
void scan1_kernel(const int* __restrict__ cnt, int* __restrict__ pre,
                  int* __restrict__ bsums, int N) {
    int r = blockIdx.y, b = blockIdx.x, t = threadIdx.x;
    int base = b * SCAN_BLK + t * SCAN_E;
    int v[SCAN_E], s = 0;
#pragma unroll
    for (int j = 0; j < SCAN_E; j++) {
        int idx = base + j;
        v[j] = (idx < N) ? cnt[(size_t)r * N + idx] : 0;
        s += v[j];
    }
    __shared__ int sd[SCAN_T];
    sd[t] = s;
    __syncthreads();
    for (int off = 1; off < SCAN_T; off <<= 1) {
        int x = (t >= off) ? sd[t - off] : 0;
        __syncthreads();
        sd[t] += x;
        __syncthreads();
    }
    if (t == SCAN_T - 1) bsums[r * gridDim.x + b] = sd[t];
    int run = sd[t] - s;  // exclusive prefix of this thread's chunk
#pragma unroll
    for (int j = 0; j < SCAN_E; j++) {
        int idx = base + j;
        if (idx < N) pre[(size_t)r * (N + 1) + idx] = run;
        run += v[j];
    }
}

__global__ void scan2_kernel(int* __restrict__ bsums, int* __restrict__ row_start,
                             int nb, int N) {
    // single thread: 3*nb values (~150) — trivial
    for (int r = 0; r < 3; r++) {
        int run = 0;
        for (int b = 0; b < nb; b++) {
            int t = bsums[r * nb + b];
            bsums[r * nb + b] = run;
            run += t;
        }
        row_start[(size_t)r * (N + 1) + N] = run;  // == E
    }
}

__global__ __launch_bounds__(SCAN_T)
void scan3_kernel(int* __restrict__ pre, const int* __restrict__ bsums,
                  int* __restrict__ cursor, int nb, int N) {
    int r = blockIdx.y, b = blockIdx.x, t = threadIdx.x;
    int add = bsums[r * nb + b];
    int base = b * SCAN_BLK + t * SCAN_E;
#pragma unroll
    for (int j = 0; j < SCAN_E; j++) {
        int idx = base + j;
        if (idx < N) {
            int val = pre[(size_t)r * (N + 1) + idx] + add;
            pre[(size_t)r * (N + 1) + idx] = val;
            cursor[(size_t)r * N + idx] = val;
        }
    }
}

__global__ __launch_bounds__(256)
void bucket_fill_kernel(const int* __restrict__ src, const int* __restrict__ dst,
                        int* __restrict__ cursor, int* __restrict__ esrc,
                        int E, int N) {
    int e = blockIdx.x * blockDim.x + threadIdx.x;
    int r = blockIdx.y;
    if (e >= E) return;
    int d = dst[(size_t)r * E + e];
    int pos = atomicAdd(cursor + (size_t)r * N + d, 1);
    esrc[(size_t)r * E + pos] = src[(size_t)r * E + e];
}

// --- C[M x 128] = (A[M x K] row-scaled by scale[M]) @ B[K x 128] -----------
__global__ __launch_bounds__(256, 2)
void gemm_rowscale(const float* __restrict__ A, const float* __restrict__ scale,
                   const float* __restrict__ B, float* __restrict__ C,
                   int M, int K) {
    __shared__ float As[BK][BM];
    __shared__ float Bs[BK][BN];

    const int tid = threadIdx.x;
    const int m0  = blockIdx.x * BM;
    const int tm  = tid >> 4;
    const int tn  = tid & 15;

    float acc[TM][TN];
#pragma unroll
    for (int i = 0; i < TM; i++)
#pragma unroll
        for (int j = 0; j < TN; j++) acc[i][j] = 0.0f;

    const int a_row = tid >> 3;
    const int a_k4  = (tid & 7) * 4;
    const int b_row = tid >> 5;
    const int b_c4  = (tid & 31) * 4;

    for (int k0 = 0; k0 < K; k0 += BK) {
#pragma unroll
        for (int i = 0; i < 4; i++) {
            int mm = a_row + i * 32;
            int m  = m0 + mm;
            float4 v = make_float4(0.f, 0.f, 0.f, 0.f);
            float  s = 0.f;
            if (m < M) {
                v = *(const float4*)(A + (size_t)m * K + k0 + a_k4);
                s = scale[m];
            }
            As[a_k4 + 0][mm] = v.x * s;
            As[a_k4 + 1][mm] = v.y * s;
            As[a_k4 + 2][mm] = v.z * s;
            As[a_k4 + 3][mm] = v.w * s;
        }
#pragma unroll
        for (int i = 0; i < 4; i++) {
            int kk = b_row + i * 8;
            *(float4*)(&Bs[kk][b_c4]) = *(const float4*)(B + (size_t)(k0 + kk) * BN + b_c4);
        }
        __syncthreads();

#pragma unroll
        for (int k = 0; k < BK; k++) {
            float a[TM], b[TN];
            *(float4*)&a[0] = *(const float4*)&As[k][tm * TM];
            *(float4*)&a[4] = *(const float4*)&As[k][tm * TM + 4];
            *(float4*)&b[0] = *(const float4*)&Bs[k][tn * TN];
            *(float4*)&b[4] = *(const float4*)&Bs[k][tn * TN + 4];
#pragma unroll
            for (int i = 0; i < TM; i++)
#pragma unroll
                for (int j = 0; j < TN; j++)
                    acc[i][j] = fmaf(a[i], b[j], acc[i][j]);
        }
        __syncthreads();
    }

#pragma unroll
    for (int i = 0; i < TM; i++) {
        int m = m0 + tm * TM + i;
        if (m < M) {
            *(float4*)(C + (size_t)m * BN + tn * TN)     = *(float4*)&acc[i][0];
            *(float4*)(C + (size_t)m * BN + tn * TN + 4) = *(float4*)&acc[i][4];
        }
    }
}

// --- CSR gather: one 64-lane wave per dst node, float2 per lane ------------
__global__ __launch_bounds__(256)
void gather_csr(const float* __restrict__ h, const int* __restrict__ row_start,
                const int* __restrict__ esrc, const float* __restrict__ s_in,
                float* __restrict__ out, int N, int accumulate) {
    int node = blockIdx.x * 4 + (threadIdx.x >> 6);
    if (node >= N) return;
    int lane = threadIdx.x & 63;
    int beg = row_start[node];
    int end = row_start[node + 1];
    float2 acc = make_float2(0.f, 0.f);
    for (int e = beg; e < end; e++) {
        int s = esrc[e];
        float2 v = *(const float2*)(h + (size_t)s * 128 + lane * 2);
        acc.x += v.x;
        acc.y += v.y;
    }
    float w = s_in[node];
    float2* op = (float2*)(out + (size_t)node * 128) + lane;
    float2 res;
    if (accumulate) {
        float2 p = *op;
        res.x = p.x + acc.x * w;
        res.y = p.y + acc.y * w;
    } else {
        res.x = acc.x * w;
        res.y = acc.y * w;
    }
    *op = res;
}

__global__ __launch_bounds__(256)
void bias_act_kernel(float* __restrict__ h, const float* __restrict__ b, int total4) {
    int i = blockIdx.x * blockDim.x + threadIdx.x;
    if (i >= total4) return;
    int g = (i & 31) * 4;
    float4 v = *(float4*)(h + (size_t)i * 4);
    float4 b0v = *(const float4*)(b + g);
    float4 b1v = *(const float4*)(b + 128 + g);
    float4 b2v = *(const float4*)(b + 256 + g);
    v.x += b0v.x + b1v.x + b2v.x;
    v.y += b0v.y + b1v.y + b2v.y;
    v.z += b0v.z + b1v.z + b2v.z;
    v.w += b0v.w + b1v.w + b2v.w;
    v.x = fmaxf(v.x, 0.f) + 0.01f * fminf(v.x, 0.f);
    v.y = fmaxf(v.y, 0.f) + 0.01f * fminf(v.y, 0.f);
    v.z = fmaxf(v.z, 0.f) + 0.01f * fminf(v.z, 0.f);
    v.w = fmaxf(v.w, 0.f) + 0.01f * fminf(v.w, 0.f);
    *(float4*)(h + (size_t)i * 4) = v;
}

__global__ __launch_bounds__(256)
void bias_only_kernel(float* __restrict__ h, const float* __restrict__ b, int total4) {
    int i = blockIdx.x * blockDim.x + threadIdx.x;
    if (i >= total4) return;
    int g = (i & 31) * 4;
    float4 v = *(float4*)(h + (size_t)i * 4);
    float4 b0v = *(const float4*)(b + g);
    float4 b1v = *(const float4*)(b + 128 + g);
    float4 b2v = *(const float4*)(b + 256 + g);
    v.x += b0v.x + b1v.x + b2v.x;
    v.y += b0v.y + b1v.y + b2v.y;
    v.z += b0v.z + b1v.z + b2v.z;
    v.w += b0v.w + b1v.w + b2v.w;
    *(float4*)(h + (size_t)i * 4) = v;
}

__global__ __launch_bounds__(256)
void logits_kernel(const float* __restrict__ h, const float* __restrict__ fcW,
                   const float* __restrict__ fcb, float* __restrict__ out, int N) {
    int i = blockIdx.x * blockDim.x + threadIdx.x;
    if (i >= N * 16) return;
    int n = i >> 4, j = i & 15;
    float acc = fcb[j];
    const float* hr = h + (size_t)n * 128;
#pragma unroll
    for (int c = 0; c < 128; c++) acc = fmaf(hr[c], fcW[c * 16 + j], acc);
    out[(size_t)n * 16 + j] = acc;
}

extern "C" void kernel_launch(void* const* d_in, const int* in_sizes, int n_in,
                              void* d_out, int out_size, void* d_ws, size_t ws_size,
                              hipStream_t stream) {
    const float* x   = (const float*)d_in[0];
    const int*   src = (const int*)d_in[1];
    const int*   dst = (const int*)d_in[2];
    const float* W0  = (const float*)d_in[3];
    const float* b0  = (const float*)d_in[4];
    const float* W1  = (const float*)d_in[5];
    const float* b1  = (const float*)d_in[6];
    const float* fcW = (const float*)d_in[7];
    const float* fcb = (const float*)d_in[8];

    const int N = in_sizes[0] / 256;   // 100000
    const int E = in_sizes[1] / 3;     // 600000
    const int nb = (N + SCAN_BLK - 1) / SCAN_BLK;  // scan blocks per relation

    float* out_h      = (float*)d_out;            // N*128
    float* out_logits = out_h + (size_t)N * 128;  // N*16

    // workspace layout (floats/ints are both 4B; keep 16B-ish alignment)
    float* s_out     = (float*)d_ws;                       // 3N
    float* s_in      = s_out + 3 * (size_t)N;              // 3N
    int*   cnt_out   = (int*)(s_in + 3 * (size_t)N);       // 3N
    int*   cnt_in    = cnt_out + 3 * (size_t)N;            // 3N
    int*   row_start = cnt_in + 3 * (size_t)N;             // 3*(N+1)
    int*   cursor    = row_start + 3 * (size_t)(N + 1);    // 3N  (+1 pad below)
    int*   bsums     = cursor + 3 * (size_t)N + 1;         // 3*nb (<256)
    int*   esrc      = bsums + 256;                        // 3E
    float* hbuf      = (float*)(esrc + 3 * (size_t)E);     // N*128
    float* acc0      = hbuf + (size_t)N * 128;             // N*128

    hipMemsetAsync(cnt_out, 0, 2 * 3 * (size_t)N * sizeof(int), stream);

    // degrees + norm scales
    hist_kernel<<<dim3((E + 255) / 256, 3), 256, 0, stream>>>(src, dst, cnt_out, cnt_in, E, N);
    scales_kernel<<<(3 * N + 255) / 256, 256, 0, stream>>>(cnt_out, cnt_in, s_out, s_in, 3 * N);

    // CSR build (dst-bucketed) per relation
    scan1_kernel<<<dim3(nb, 3), SCAN_T, 0, stream>>>(cnt_in, row_start, bsums, N);
    scan2_kernel<<<1, 1, 0, stream>>>(bsums, row_start, nb, N);
    scan3_kernel<<<dim3(nb, 3), SCAN_T, 0, stream>>>(row_start, bsums, cursor, nb, N);
    bucket_fill_kernel<<<dim3((E + 255) / 256, 3), 256, 0, stream>>>(src, dst, cursor, esrc, E, N);

    int gemm_blocks   = (N + BM - 1) / BM;
    int gather_blocks = (N + 3) / 4;

    // Layer 0: x[N,256] -> acc0[N,128]
    for (int r = 0; r < 3; r++) {
        gemm_rowscale<<<gemm_blocks, 256, 0, stream>>>(
            x, s_out + (size_t)r * N, W0 + (size_t)r * 256 * 128, hbuf, N, 256);
        gather_csr<<<gather_blocks, 256, 0, stream>>>(
            hbuf, row_start + (size_t)r * (N + 1), esrc + (size_t)r * E,
            s_in + (size_t)r * N, acc0, N, r > 0);
    }
    bias_act_kernel<<<(N * 32 + 255) / 256, 256, 0, stream>>>(acc0, b0, N * 32);

    // Layer 1: acc0[N,128] -> out_h[N,128]
    for (int r = 0; r < 3; r++) {
        gemm_rowscale<<<gemm_blocks, 256, 0, stream>>>(
            acc0, s_out + (size_t)r * N, W1 + (size_t)r * 128 * 128, hbuf, N, 128);
        gather_csr<<<gather_blocks, 256, 0, stream>>>(
            hbuf, row_start + (size_t)r * (N + 1), esrc + (size_t)r * E,
            s_in + (size_t)r * N, out_h, N, r > 0);
    }
    bias_only_kernel<<<(N * 32 + 255) / 256, 256, 0, stream>>>(out_h, b1, N * 32);

    logits_kernel<<<(N * 16 + 255) / 256, 256, 0, stream>>>(out_h, fcW, fcb, out_logits, N);
}

// Round 3
// 957.497 us; speedup vs baseline: 7.2255x; 1.5555x over previous
//
#include <hip/hip_runtime.h>
#include <hip/hip_bf16.h>
#include <stdint.h>

// ---------------------------------------------------------------------------
// HeteroTextGCN round 3:
//  - GEMMs: bf16 hi/lo split (3 MFMAs/tile, fp32-class accuracy) on matrix
//    cores; outputs stored bf16 (halves gather traffic).
//  - Gather: one fused kernel per layer (3 relations + bias + activation;
//    layer 1 also computes logits via wave shuffle reduction).
//  - CSR build (hist/scan/bucket_fill) unchanged from round 2.
// ---------------------------------------------------------------------------

typedef __attribute__((ext_vector_type(8))) short bf16x8;
typedef __attribute__((ext_vector_type(4))) float f32x4;
typedef unsigned short u16;

#define SCAN_T 256
#define SCAN_E 8
#define SCAN_BLK (SCAN_T * SCAN_E)

__global__ __launch_bounds__(256)
void hist_kernel(const int* __restrict__ src, const int* __restrict__ dst,
                 int* __restrict__ cnt_out, int* __restrict__ cnt_in,
                 int E, int N) {
    int e = blockIdx.x * blockDim.x + threadIdx.x;
    int r = blockIdx.y;
    if (e >= E) return;
    atomicAdd(cnt_out + (size_t)r * N + src[(size_t)r * E + e], 1);
    atomicAdd(cnt_in  + (size_t)r * N + dst[(size_t)r * E + e], 1);
}

__global__ __launch_bounds__(256)
void scales_kernel(const int* __restrict__ cnt_out, const int* __restrict__ cnt_in,
                   float* __restrict__ s_out, float* __restrict__ s_in, int total) {
    int i = blockIdx.x * blockDim.x + threadIdx.x;
    if (i >= total) return;
    s_out[i] = rsqrtf(fmaxf((float)cnt_out[i], 1.0f));
    s_in[i]  = rsqrtf(fmaxf((float)cnt_in[i],  1.0f));
}

__global__ __launch_bounds__(SCAN_T)
void scan1_kernel(const int* __restrict__ cnt, int* __restrict__ pre,
                  int* __restrict__ bsums, int N) {
    int r = blockIdx.y, b = blockIdx.x, t = threadIdx.x;
    int base = b * SCAN_BLK + t * SCAN_E;
    int v[SCAN_E], s = 0;
#pragma unroll
    for (int j = 0; j < SCAN_E; j++) {
        int idx = base + j;
        v[j] = (idx < N) ? cnt[(size_t)r * N + idx] : 0;
        s += v[j];
    }
    __shared__ int sd[SCAN_T];
    sd[t] = s;
    __syncthreads();
    for (int off = 1; off < SCAN_T; off <<= 1) {
        int x = (t >= off) ? sd[t - off] : 0;
        __syncthreads();
        sd[t] += x;
        __syncthreads();
    }
    if (t == SCAN_T - 1) bsums[r * gridDim.x + b] = sd[t];
    int run = sd[t] - s;
#pragma unroll
    for (int j = 0; j < SCAN_E; j++) {
        int idx = base + j;
        if (idx < N) pre[(size_t)r * (N + 1) + idx] = run;
        run += v[j];
    }
}

__global__ void scan2_kernel(int* __restrict__ bsums, int* __restrict__ row_start,
                             int nb, int N) {
    for (int r = 0; r < 3; r++) {
        int run = 0;
        for (int b = 0; b < nb; b++) {
            int t = bsums[r * nb + b];
            bsums[r * nb + b] = run;
            run += t;
        }
        row_start[(size_t)r * (N + 1) + N] = run;
    }
}

__global__ __launch_bounds__(SCAN_T)
void scan3_kernel(int* __restrict__ pre, const int* __restrict__ bsums,
                  int* __restrict__ cursor, int nb, int N) {
    int r = blockIdx.y, b = blockIdx.x, t = threadIdx.x;
    int add = bsums[r * nb + b];
    int base = b * SCAN_BLK + t * SCAN_E;
#pragma unroll
    for (int j = 0; j < SCAN_E; j++) {
        int idx = base + j;
        if (idx < N) {
            int val = pre[(size_t)r * (N + 1) + idx] + add;
            pre[(size_t)r * (N + 1) + idx] = val;
            cursor[(size_t)r * N + idx] = val;
        }
    }
}

__global__ __launch_bounds__(256)
void bucket_fill_kernel(const int* __restrict__ src, const int* __restrict__ dst,
                        int* __restrict__ cursor, int* __restrict__ esrc,
                        int E, int N) {
    int e = blockIdx.x * blockDim.x + threadIdx.x;
    int r = blockIdx.y;
    if (e >= E) return;
    int d = dst[(size_t)r * E + e];
    int pos = atomicAdd(cursor + (size_t)r * N + d, 1);
    esrc[(size_t)r * E + pos] = src[(size_t)r * E + e];
}

// --- pre-split W0/W1 into hi/lo bf16, transposed to [r][n][k] --------------
// W0: 3 x 256 x 128 (k-major), W1: 3 x 128 x 128.
__global__ __launch_bounds__(256)
void prep_w_kernel(const float* __restrict__ W0, const float* __restrict__ W1,
                   u16* __restrict__ w0hi, u16* __restrict__ w0lo,
                   u16* __restrict__ w1hi, u16* __restrict__ w1lo) {
    int idx = blockIdx.x * blockDim.x + threadIdx.x;
    const int n0 = 3 * 256 * 128;
    const int n1 = 3 * 128 * 128;
    if (idx >= n0 + n1) return;
    float f;
    u16 *phi, *plo;
    int oidx;
    if (idx < n0) {
        int r = idx / 32768, rem = idx % 32768;
        int n = rem / 256, k = rem % 256;
        f = W0[(size_t)r * 32768 + (size_t)k * 128 + n];
        phi = w0hi; plo = w0lo; oidx = idx;
    } else {
        int i2 = idx - n0;
        int r = i2 / 16384, rem = i2 % 16384;
        int n = rem / 128, k = rem % 128;
        f = W1[(size_t)r * 16384 + (size_t)k * 128 + n];
        phi = w1hi; plo = w1lo; oidx = i2;
    }
    uint32_t u = __float_as_uint(f);
    phi[oidx] = (u16)(u >> 16);                     // truncated hi
    float lo = f - __uint_as_float(u & 0xFFFF0000u);
    uint32_t ul = __float_as_uint(lo);
    plo[oidx] = (u16)((ul + 0x7FFFu + ((ul >> 16) & 1u)) >> 16);  // RTNE lo
}

// --- C[M x 128](bf16) = round_bf16((A[M x K] * scale[M]) @ W[K x 128]) -----
// bf16 hi/lo split: A*B ~= Ahi*Bhi + Alo*Bhi + Ahi*Blo  (fp32 accumulate)
__global__ __launch_bounds__(256)
void gemm_split_bf16(const float* __restrict__ A, const float* __restrict__ scale,
                     const u16* __restrict__ Whi, const u16* __restrict__ Wlo,
                     u16* __restrict__ Cout, int M, int K) {
    __shared__ u16 As_hi[128][40];   // [m][k], +8 pad breaks bank conflicts
    __shared__ u16 As_lo[128][40];
    __shared__ u16 Bs_hi[128][40];   // [n][k]
    __shared__ u16 Bs_lo[128][40];

    const int tid  = threadIdx.x;
    const int m0   = blockIdx.x * 128;
    const int lane = tid & 63;
    const int wave = tid >> 6;
    const int wm   = (wave & 1) * 64;
    const int wn   = (wave >> 1) * 64;
    const int lm   = lane & 15;
    const int kq   = (lane >> 4) * 8;

    f32x4 acc[4][4];
#pragma unroll
    for (int i = 0; i < 4; i++)
#pragma unroll
        for (int j = 0; j < 4; j++) acc[i][j] = (f32x4){0.f, 0.f, 0.f, 0.f};

    const int srow = tid >> 1;           // 0..127
    const int skb  = (tid & 1) * 16;     // k sub-offset

    const bool valid = (m0 + srow) < M;
    const float sval = valid ? scale[m0 + srow] : 0.f;
    const float* arow = A + (size_t)(m0 + srow) * K;
    const u16* whrow = Whi + (size_t)srow * K;
    const u16* wlrow = Wlo + (size_t)srow * K;

    for (int k0 = 0; k0 < K; k0 += 32) {
        // ---- stage A (fp32 -> scaled -> hi/lo bf16) ----
        float fa[16];
        if (valid) {
            *(float4*)&fa[0]  = *(const float4*)(arow + k0 + skb);
            *(float4*)&fa[4]  = *(const float4*)(arow + k0 + skb + 4);
            *(float4*)&fa[8]  = *(const float4*)(arow + k0 + skb + 8);
            *(float4*)&fa[12] = *(const float4*)(arow + k0 + skb + 12);
        } else {
#pragma unroll
            for (int i = 0; i < 16; i++) fa[i] = 0.f;
        }
        uint32_t ah[8], al[8];
#pragma unroll
        for (int p = 0; p < 8; p++) {
            float f0 = fa[2 * p] * sval, f1 = fa[2 * p + 1] * sval;
            uint32_t u0 = __float_as_uint(f0), u1 = __float_as_uint(f1);
            ah[p] = (u0 >> 16) | (u1 & 0xFFFF0000u);
            float l0 = f0 - __uint_as_float(u0 & 0xFFFF0000u);
            float l1 = f1 - __uint_as_float(u1 & 0xFFFF0000u);
            al[p] = (__float_as_uint(l0) >> 16) | (__float_as_uint(l1) & 0xFFFF0000u);
        }
        *(uint4*)&As_hi[srow][skb]     = *(uint4*)&ah[0];
        *(uint4*)&As_hi[srow][skb + 8] = *(uint4*)&ah[4];
        *(uint4*)&As_lo[srow][skb]     = *(uint4*)&al[0];
        *(uint4*)&As_lo[srow][skb + 8] = *(uint4*)&al[4];

        // ---- stage B (pre-split, pre-transposed) ----
        *(uint4*)&Bs_hi[srow][skb]     = *(const uint4*)(whrow + k0 + skb);
        *(uint4*)&Bs_hi[srow][skb + 8] = *(const uint4*)(whrow + k0 + skb + 8);
        *(uint4*)&Bs_lo[srow][skb]     = *(const uint4*)(wlrow + k0 + skb);
        *(uint4*)&Bs_lo[srow][skb + 8] = *(const uint4*)(wlrow + k0 + skb + 8);

        __syncthreads();

        bf16x8 a_hi[4], a_lo[4], b_hi[4], b_lo[4];
#pragma unroll
        for (int i = 0; i < 4; i++) {
            a_hi[i] = *(const bf16x8*)&As_hi[wm + i * 16 + lm][kq];
            a_lo[i] = *(const bf16x8*)&As_lo[wm + i * 16 + lm][kq];
            b_hi[i] = *(const bf16x8*)&Bs_hi[wn + i * 16 + lm][kq];
            b_lo[i] = *(const bf16x8*)&Bs_lo[wn + i * 16 + lm][kq];
        }
#pragma unroll
        for (int i = 0; i < 4; i++)
#pragma unroll
            for (int j = 0; j < 4; j++) {
                acc[i][j] = __builtin_amdgcn_mfma_f32_16x16x32_bf16(a_hi[i], b_hi[j], acc[i][j], 0, 0, 0);
                acc[i][j] = __builtin_amdgcn_mfma_f32_16x16x32_bf16(a_lo[i], b_hi[j], acc[i][j], 0, 0, 0);
                acc[i][j] = __builtin_amdgcn_mfma_f32_16x16x32_bf16(a_hi[i], b_lo[j], acc[i][j], 0, 0, 0);
            }
        __syncthreads();
    }

    // epilogue: C/D layout col=lane&15, row=(lane>>4)*4+reg; store RTNE bf16
    const int rq = (lane >> 4) * 4;
#pragma unroll
    for (int i = 0; i < 4; i++) {
        int mbase = m0 + wm + i * 16 + rq;
#pragma unroll
        for (int j = 0; j < 4; j++) {
            int col = wn + j * 16 + lm;
#pragma unroll
            for (int rg = 0; rg < 4; rg++) {
                int m = mbase + rg;
                if (m < M) {
                    uint32_t u = __float_as_uint(acc[i][j][rg]);
                    Cout[(size_t)m * 128 + col] =
                        (u16)((u + 0x7FFFu + ((u >> 16) & 1u)) >> 16);
                }
            }
        }
    }
}

// --- fused gather layer 0: 3 relations + bias + leakyReLU -> acc0 (fp32) ---
__global__ __launch_bounds__(256)
void gather_l0(const u16* __restrict__ hb, const int* __restrict__ row_start,
               const int* __restrict__ esrc, const float* __restrict__ s_in,
               const float* __restrict__ b, float* __restrict__ out, int N, int E) {
    int node = blockIdx.x * 4 + (threadIdx.x >> 6);
    if (node >= N) return;
    int lane = threadIdx.x & 63;
    float tx = 0.f, ty = 0.f;
#pragma unroll
    for (int r = 0; r < 3; r++) {
        const int* rs = row_start + (size_t)r * (N + 1);
        const int* es = esrc + (size_t)r * E;
        const uint32_t* h = (const uint32_t*)hb + (size_t)r * N * 64 + lane;
        int beg = rs[node], end = rs[node + 1];
        float ax = 0.f, ay = 0.f, cx = 0.f, cy = 0.f;
        int e = beg;
        for (; e + 1 < end; e += 2) {
            int s0 = es[e], s1 = es[e + 1];
            uint32_t u0 = h[(size_t)s0 * 64];
            uint32_t u1 = h[(size_t)s1 * 64];
            ax += __uint_as_float(u0 << 16);
            ay += __uint_as_float(u0 & 0xFFFF0000u);
            cx += __uint_as_float(u1 << 16);
            cy += __uint_as_float(u1 & 0xFFFF0000u);
        }
        if (e < end) {
            uint32_t u0 = h[(size_t)es[e] * 64];
            ax += __uint_as_float(u0 << 16);
            ay += __uint_as_float(u0 & 0xFFFF0000u);
        }
        float w = s_in[(size_t)r * N + node];
        tx += (ax + cx) * w;
        ty += (ay + cy) * w;
    }
    int c0 = lane * 2;
    tx += b[c0] + b[128 + c0] + b[256 + c0];
    ty += b[c0 + 1] + b[128 + c0 + 1] + b[256 + c0 + 1];
    tx = fmaxf(tx, 0.f) + 0.01f * fminf(tx, 0.f);
    ty = fmaxf(ty, 0.f) + 0.01f * fminf(ty, 0.f);
    *(float2*)(out + (size_t)node * 128 + c0) = make_float2(tx, ty);
}

// --- fused gather layer 1: 3 relations + bias -> out_h; + logits -----------
__global__ __launch_bounds__(256)
void gather_l1(const u16* __restrict__ hb, const int* __restrict__ row_start,
               const int* __restrict__ esrc, const float* __restrict__ s_in,
               const float* __restrict__ b, const float* __restrict__ fcW,
               const float* __restrict__ fcb, float* __restrict__ out_h,
               float* __restrict__ out_logits, int N, int E) {
    int node = blockIdx.x * 4 + (threadIdx.x >> 6);
    if (node >= N) return;
    int lane = threadIdx.x & 63;
    float tx = 0.f, ty = 0.f;
#pragma unroll
    for (int r = 0; r < 3; r++) {
        const int* rs = row_start + (size_t)r * (N + 1);
        const int* es = esrc + (size_t)r * E;
        const uint32_t* h = (const uint32_t*)hb + (size_t)r * N * 64 + lane;
        int beg = rs[node], end = rs[node + 1];
        float ax = 0.f, ay = 0.f, cx = 0.f, cy = 0.f;
        int e = beg;
        for (; e + 1 < end; e += 2) {
            int s0 = es[e], s1 = es[e + 1];
            uint32_t u0 = h[(size_t)s0 * 64];
            uint32_t u1 = h[(size_t)s1 * 64];
            ax += __uint_as_float(u0 << 16);
            ay += __uint_as_float(u0 & 0xFFFF0000u);
            cx += __uint_as_float(u1 << 16);
            cy += __uint_as_float(u1 & 0xFFFF0000u);
        }
        if (e < end) {
            uint32_t u0 = h[(size_t)es[e] * 64];
            ax += __uint_as_float(u0 << 16);
            ay += __uint_as_float(u0 & 0xFFFF0000u);
        }
        float w = s_in[(size_t)r * N + node];
        tx += (ax + cx) * w;
        ty += (ay + cy) * w;
    }
    int c0 = lane * 2;
    tx += b[c0] + b[128 + c0] + b[256 + c0];
    ty += b[c0 + 1] + b[128 + c0 + 1] + b[256 + c0 + 1];
    *(float2*)(out_h + (size_t)node * 128 + c0) = make_float2(tx, ty);

    // logits: per-lane partials over the 2 owned channels, butterfly-reduce
    const float* fc0 = fcW + (size_t)c0 * 16;
    float p[16];
#pragma unroll
    for (int j = 0; j < 16; j++) p[j] = tx * fc0[j] + ty * fc0[16 + j];
#pragma unroll
    for (int off = 1; off < 64; off <<= 1) {
#pragma unroll
        for (int j = 0; j < 16; j++) p[j] += __shfl_xor(p[j], off);
    }
    if (lane == 0) {
        float* lp = out_logits + (size_t)node * 16;
        *(float4*)(lp + 0)  = make_float4(p[0] + fcb[0],  p[1] + fcb[1],  p[2] + fcb[2],  p[3] + fcb[3]);
        *(float4*)(lp + 4)  = make_float4(p[4] + fcb[4],  p[5] + fcb[5],  p[6] + fcb[6],  p[7] + fcb[7]);
        *(float4*)(lp + 8)  = make_float4(p[8] + fcb[8],  p[9] + fcb[9],  p[10] + fcb[10], p[11] + fcb[11]);
        *(float4*)(lp + 12) = make_float4(p[12] + fcb[12], p[13] + fcb[13], p[14] + fcb[14], p[15] + fcb[15]);
    }
}

extern "C" void kernel_launch(void* const* d_in, const int* in_sizes, int n_in,
                              void* d_out, int out_size, void* d_ws, size_t ws_size,
                              hipStream_t stream) {
    const float* x   = (const float*)d_in[0];
    const int*   src = (const int*)d_in[1];
    const int*   dst = (const int*)d_in[2];
    const float* W0  = (const float*)d_in[3];
    const float* b0  = (const float*)d_in[4];
    const float* W1  = (const float*)d_in[5];
    const float* b1  = (const float*)d_in[6];
    const float* fcW = (const float*)d_in[7];
    const float* fcb = (const float*)d_in[8];

    const int N = in_sizes[0] / 256;   // 100000
    const int E = in_sizes[1] / 3;     // 600000
    const int nb = (N + SCAN_BLK - 1) / SCAN_BLK;

    float* out_h      = (float*)d_out;
    float* out_logits = out_h + (size_t)N * 128;

    // workspace layout (256B-aligned chunks)
    char* p = (char*)d_ws;
    auto alloc = [&](size_t bytes) -> char* {
        char* q = p;
        p += (bytes + 255) & ~(size_t)255;
        return q;
    };
    float* s_out     = (float*)alloc(3 * (size_t)N * 4);
    float* s_in      = (float*)alloc(3 * (size_t)N * 4);
    int*   cnt_out   = (int*)alloc(3 * (size_t)N * 4);
    int*   cnt_in    = (int*)alloc(3 * (size_t)N * 4);
    int*   row_start = (int*)alloc(3 * (size_t)(N + 1) * 4);
    int*   cursor    = (int*)alloc(3 * (size_t)N * 4);
    int*   bsums     = (int*)alloc(1024 * 4);
    int*   esrc      = (int*)alloc(3 * (size_t)E * 4);
    u16*   w0hi      = (u16*)alloc(3 * 256 * 128 * 2);
    u16*   w0lo      = (u16*)alloc(3 * 256 * 128 * 2);
    u16*   w1hi      = (u16*)alloc(3 * 128 * 128 * 2);
    u16*   w1lo      = (u16*)alloc(3 * 128 * 128 * 2);
    u16*   hb        = (u16*)alloc(3 * (size_t)N * 128 * 2);
    float* acc0      = (float*)alloc((size_t)N * 128 * 4);

    hipMemsetAsync(cnt_out, 0, 3 * (size_t)N * sizeof(int), stream);
    hipMemsetAsync(cnt_in,  0, 3 * (size_t)N * sizeof(int), stream);

    hist_kernel<<<dim3((E + 255) / 256, 3), 256, 0, stream>>>(src, dst, cnt_out, cnt_in, E, N);
    scales_kernel<<<(3 * N + 255) / 256, 256, 0, stream>>>(cnt_out, cnt_in, s_out, s_in, 3 * N);

    scan1_kernel<<<dim3(nb, 3), SCAN_T, 0, stream>>>(cnt_in, row_start, bsums, N);
    scan2_kernel<<<1, 1, 0, stream>>>(bsums, row_start, nb, N);
    scan3_kernel<<<dim3(nb, 3), SCAN_T, 0, stream>>>(row_start, bsums, cursor, nb, N);
    bucket_fill_kernel<<<dim3((E + 255) / 256, 3), 256, 0, stream>>>(src, dst, cursor, esrc, E, N);

    prep_w_kernel<<<(3 * 256 * 128 + 3 * 128 * 128 + 255) / 256, 256, 0, stream>>>(
        W0, W1, w0hi, w0lo, w1hi, w1lo);

    int gemm_blocks   = (N + 127) / 128;
    int gather_blocks = (N + 3) / 4;

    // Layer 0: x[N,256] -> hb[r][N,128] bf16 -> acc0[N,128] fp32
    for (int r = 0; r < 3; r++) {
        gemm_split_bf16<<<gemm_blocks, 256, 0, stream>>>(
            x, s_out + (size_t)r * N, w0hi + (size_t)r * 32768, w0lo + (size_t)r * 32768,
            hb + (size_t)r * N * 128, N, 256);
    }
    gather_l0<<<gather_blocks, 256, 0, stream>>>(hb, row_start, esrc, s_in, b0, acc0, N, E);

    // Layer 1: acc0[N,128] -> hb[r][N,128] bf16 -> out_h + logits
    for (int r = 0; r < 3; r++) {
        gemm_split_bf16<<<gemm_blocks, 256, 0, stream>>>(
            acc0, s_out + (size_t)r * N, w1hi + (size_t)r * 16384, w1lo + (size_t)r * 16384,
            hb + (size_t)r * N * 128, N, 128);
    }
    gather_l1<<<gather_blocks, 256, 0, stream>>>(hb, row_start, esrc, s_in, b1, fcW, fcb,
                                                 out_h, out_logits, N, E);
}

// Round 4
// 846.263 us; speedup vs baseline: 8.1752x; 1.1314x over previous
//
#include <hip/hip_runtime.h>
#include <hip/hip_bf16.h>
#include <stdint.h>

// ---------------------------------------------------------------------------
// HeteroTextGCN round 4:
//  - gather: unroll-4 edge batches (MLP 2->4) — was memory-latency bound
//  - hist: 8 per-XCD counter copies (blockIdx&7) -> XCD-local atomics,
//    fused 8-way reduce + rsqrt scales kernel
//  - GEMMs: 3 relations merged into one dispatch (grid.y = relation)
// ---------------------------------------------------------------------------

typedef __attribute__((ext_vector_type(8))) short bf16x8;
typedef __attribute__((ext_vector_type(4))) float f32x4;
typedef unsigned short u16;

#define SCAN_T 256
#define SCAN_E 8
#define SCAN_BLK (SCAN_T * SCAN_E)

// --- degree histograms into 8 per-XCD copies -------------------------------
__global__ __launch_bounds__(256)
void hist_kernel(const int* __restrict__ src, const int* __restrict__ dst,
                 int* __restrict__ cnt_out8, int* __restrict__ cnt_in8,
                 int E, int N) {
    int e = blockIdx.x * blockDim.x + threadIdx.x;
    int r = blockIdx.y;
    if (e >= E) return;
    // round-robin block->XCD heuristic; wrong mapping = slower, never wrong
    int copy = blockIdx.x & 7;
    size_t base = ((size_t)copy * 3 + r) * N;
    atomicAdd(cnt_out8 + base + src[(size_t)r * E + e], 1);
    atomicAdd(cnt_in8  + base + dst[(size_t)r * E + e], 1);
}

// --- reduce 8 copies + compute scales + emit cnt_in for the scan -----------
__global__ __launch_bounds__(256)
void reduce_scales_kernel(const int* __restrict__ cnt_out8, const int* __restrict__ cnt_in8,
                          float* __restrict__ s_out, float* __restrict__ s_in,
                          int* __restrict__ cnt_in, int total /*3N*/) {
    int i = blockIdx.x * blockDim.x + threadIdx.x;
    if (i >= total) return;
    int co = 0, ci = 0;
#pragma unroll
    for (int c = 0; c < 8; c++) {
        co += cnt_out8[(size_t)c * total + i];
        ci += cnt_in8[(size_t)c * total + i];
    }
    s_out[i] = rsqrtf(fmaxf((float)co, 1.0f));
    s_in[i]  = rsqrtf(fmaxf((float)ci, 1.0f));
    cnt_in[i] = ci;
}

__global__ __launch_bounds__(SCAN_T)
void scan1_kernel(const int* __restrict__ cnt, int* __restrict__ pre,
                  int* __restrict__ bsums, int N) {
    int r = blockIdx.y, b = blockIdx.x, t = threadIdx.x;
    int base = b * SCAN_BLK + t * SCAN_E;
    int v[SCAN_E], s = 0;
#pragma unroll
    for (int j = 0; j < SCAN_E; j++) {
        int idx = base + j;
        v[j] = (idx < N) ? cnt[(size_t)r * N + idx] : 0;
        s += v[j];
    }
    __shared__ int sd[SCAN_T];
    sd[t] = s;
    __syncthreads();
    for (int off = 1; off < SCAN_T; off <<= 1) {
        int x = (t >= off) ? sd[t - off] : 0;
        __syncthreads();
        sd[t] += x;
        __syncthreads();
    }
    if (t == SCAN_T - 1) bsums[r * gridDim.x + b] = sd[t];
    int run = sd[t] - s;
#pragma unroll
    for (int j = 0; j < SCAN_E; j++) {
        int idx = base + j;
        if (idx < N) pre[(size_t)r * (N + 1) + idx] = run;
        run += v[j];
    }
}

__global__ void scan2_kernel(int* __restrict__ bsums, int* __restrict__ row_start,
                             int nb, int N) {
    for (int r = 0; r < 3; r++) {
        int run = 0;
        for (int b = 0; b < nb; b++) {
            int t = bsums[r * nb + b];
            bsums[r * nb + b] = run;
            run += t;
        }
        row_start[(size_t)r * (N + 1) + N] = run;
    }
}

__global__ __launch_bounds__(SCAN_T)
void scan3_kernel(int* __restrict__ pre, const int* __restrict__ bsums,
                  int* __restrict__ cursor, int nb, int N) {
    int r = blockIdx.y, b = blockIdx.x, t = threadIdx.x;
    int add = bsums[r * nb + b];
    int base = b * SCAN_BLK + t * SCAN_E;
#pragma unroll
    for (int j = 0; j < SCAN_E; j++) {
        int idx = base + j;
        if (idx < N) {
            int val = pre[(size_t)r * (N + 1) + idx] + add;
            pre[(size_t)r * (N + 1) + idx] = val;
            cursor[(size_t)r * N + idx] = val;
        }
    }
}

__global__ __launch_bounds__(256)
void bucket_fill_kernel(const int* __restrict__ src, const int* __restrict__ dst,
                        int* __restrict__ cursor, int* __restrict__ esrc,
                        int E, int N) {
    int e = blockIdx.x * blockDim.x + threadIdx.x;
    int r = blockIdx.y;
    if (e >= E) return;
    int d = dst[(size_t)r * E + e];
    int pos = atomicAdd(cursor + (size_t)r * N + d, 1);
    esrc[(size_t)r * E + pos] = src[(size_t)r * E + e];
}

// --- pre-split W0/W1 into hi/lo bf16, transposed to [r][n][k] --------------
__global__ __launch_bounds__(256)
void prep_w_kernel(const float* __restrict__ W0, const float* __restrict__ W1,
                   u16* __restrict__ w0hi, u16* __restrict__ w0lo,
                   u16* __restrict__ w1hi, u16* __restrict__ w1lo) {
    int idx = blockIdx.x * blockDim.x + threadIdx.x;
    const int n0 = 3 * 256 * 128;
    const int n1 = 3 * 128 * 128;
    if (idx >= n0 + n1) return;
    float f;
    u16 *phi, *plo;
    int oidx;
    if (idx < n0) {
        int r = idx / 32768, rem = idx % 32768;
        int n = rem / 256, k = rem % 256;
        f = W0[(size_t)r * 32768 + (size_t)k * 128 + n];
        phi = w0hi; plo = w0lo; oidx = idx;
    } else {
        int i2 = idx - n0;
        int r = i2 / 16384, rem = i2 % 16384;
        int n = rem / 128, k = rem % 128;
        f = W1[(size_t)r * 16384 + (size_t)k * 128 + n];
        phi = w1hi; plo = w1lo; oidx = i2;
    }
    uint32_t u = __float_as_uint(f);
    phi[oidx] = (u16)(u >> 16);                     // truncated hi
    float lo = f - __uint_as_float(u & 0xFFFF0000u);
    uint32_t ul = __float_as_uint(lo);
    plo[oidx] = (u16)((ul + 0x7FFFu + ((ul >> 16) & 1u)) >> 16);  // RTNE lo
}

// --- C_r[M x 128](bf16) = round_bf16((A * scale_r) @ W_r), r = blockIdx.y --
__global__ __launch_bounds__(256)
void gemm_split_bf16(const float* __restrict__ A, const float* __restrict__ s_out,
                     const u16* __restrict__ Whi_all, const u16* __restrict__ Wlo_all,
                     u16* __restrict__ Cout_all, int M, int K, int Nn) {
    const int r = blockIdx.y;
    const float* scale = s_out + (size_t)r * Nn;
    const u16* Whi = Whi_all + (size_t)r * K * 128;
    const u16* Wlo = Wlo_all + (size_t)r * K * 128;
    u16* Cout = Cout_all + (size_t)r * Nn * 128;

    __shared__ u16 As_hi[128][40];
    __shared__ u16 As_lo[128][40];
    __shared__ u16 Bs_hi[128][40];
    __shared__ u16 Bs_lo[128][40];

    const int tid  = threadIdx.x;
    const int m0   = blockIdx.x * 128;
    const int lane = tid & 63;
    const int wave = tid >> 6;
    const int wm   = (wave & 1) * 64;
    const int wn   = (wave >> 1) * 64;
    const int lm   = lane & 15;
    const int kq   = (lane >> 4) * 8;

    f32x4 acc[4][4];
#pragma unroll
    for (int i = 0; i < 4; i++)
#pragma unroll
        for (int j = 0; j < 4; j++) acc[i][j] = (f32x4){0.f, 0.f, 0.f, 0.f};

    const int srow = tid >> 1;
    const int skb  = (tid & 1) * 16;

    const bool valid = (m0 + srow) < M;
    const float sval = valid ? scale[m0 + srow] : 0.f;
    const float* arow = A + (size_t)(m0 + srow) * K;
    const u16* whrow = Whi + (size_t)srow * K;
    const u16* wlrow = Wlo + (size_t)srow * K;

    for (int k0 = 0; k0 < K; k0 += 32) {
        float fa[16];
        if (valid) {
            *(float4*)&fa[0]  = *(const float4*)(arow + k0 + skb);
            *(float4*)&fa[4]  = *(const float4*)(arow + k0 + skb + 4);
            *(float4*)&fa[8]  = *(const float4*)(arow + k0 + skb + 8);
            *(float4*)&fa[12] = *(const float4*)(arow + k0 + skb + 12);
        } else {
#pragma unroll
            for (int i = 0; i < 16; i++) fa[i] = 0.f;
        }
        uint32_t ah[8], al[8];
#pragma unroll
        for (int p = 0; p < 8; p++) {
            float f0 = fa[2 * p] * sval, f1 = fa[2 * p + 1] * sval;
            uint32_t u0 = __float_as_uint(f0), u1 = __float_as_uint(f1);
            ah[p] = (u0 >> 16) | (u1 & 0xFFFF0000u);
            float l0 = f0 - __uint_as_float(u0 & 0xFFFF0000u);
            float l1 = f1 - __uint_as_float(u1 & 0xFFFF0000u);
            al[p] = (__float_as_uint(l0) >> 16) | (__float_as_uint(l1) & 0xFFFF0000u);
        }
        *(uint4*)&As_hi[srow][skb]     = *(uint4*)&ah[0];
        *(uint4*)&As_hi[srow][skb + 8] = *(uint4*)&ah[4];
        *(uint4*)&As_lo[srow][skb]     = *(uint4*)&al[0];
        *(uint4*)&As_lo[srow][skb + 8] = *(uint4*)&al[4];

        *(uint4*)&Bs_hi[srow][skb]     = *(const uint4*)(whrow + k0 + skb);
        *(uint4*)&Bs_hi[srow][skb + 8] = *(const uint4*)(whrow + k0 + skb + 8);
        *(uint4*)&Bs_lo[srow][skb]     = *(const uint4*)(wlrow + k0 + skb);
        *(uint4*)&Bs_lo[srow][skb + 8] = *(const uint4*)(wlrow + k0 + skb + 8);

        __syncthreads();

        bf16x8 a_hi[4], a_lo[4], b_hi[4], b_lo[4];
#pragma unroll
        for (int i = 0; i < 4; i++) {
            a_hi[i] = *(const bf16x8*)&As_hi[wm + i * 16 + lm][kq];
            a_lo[i] = *(const bf16x8*)&As_lo[wm + i * 16 + lm][kq];
            b_hi[i] = *(const bf16x8*)&Bs_hi[wn + i * 16 + lm][kq];
            b_lo[i] = *(const bf16x8*)&Bs_lo[wn + i * 16 + lm][kq];
        }
#pragma unroll
        for (int i = 0; i < 4; i++)
#pragma unroll
            for (int j = 0; j < 4; j++) {
                acc[i][j] = __builtin_amdgcn_mfma_f32_16x16x32_bf16(a_hi[i], b_hi[j], acc[i][j], 0, 0, 0);
                acc[i][j] = __builtin_amdgcn_mfma_f32_16x16x32_bf16(a_lo[i], b_hi[j], acc[i][j], 0, 0, 0);
                acc[i][j] = __builtin_amdgcn_mfma_f32_16x16x32_bf16(a_hi[i], b_lo[j], acc[i][j], 0, 0, 0);
            }
        __syncthreads();
    }

    const int rq = (lane >> 4) * 4;
#pragma unroll
    for (int i = 0; i < 4; i++) {
        int mbase = m0 + wm + i * 16 + rq;
#pragma unroll
        for (int j = 0; j < 4; j++) {
            int col = wn + j * 16 + lm;
#pragma unroll
            for (int rg = 0; rg < 4; rg++) {
                int m = mbase + rg;
                if (m < M) {
                    uint32_t u = __float_as_uint(acc[i][j][rg]);
                    Cout[(size_t)m * 128 + col] =
                        (u16)((u + 0x7FFFu + ((u >> 16) & 1u)) >> 16);
                }
            }
        }
    }
}

#define BF16_LO(u) __uint_as_float((u) << 16)
#define BF16_HI(u) __uint_as_float((u) & 0xFFFF0000u)

// per-relation edge accumulation, 4 loads in flight
__device__ __forceinline__ void gather_rel(const uint32_t* __restrict__ h,
                                           const int* __restrict__ es,
                                           int beg, int end,
                                           float& ox, float& oy, float w) {
    float ax = 0.f, ay = 0.f, cx = 0.f, cy = 0.f;
    int e = beg;
    for (; e + 4 <= end; e += 4) {
        int s0 = es[e], s1 = es[e + 1], s2 = es[e + 2], s3 = es[e + 3];
        uint32_t u0 = h[(size_t)s0 * 64];
        uint32_t u1 = h[(size_t)s1 * 64];
        uint32_t u2 = h[(size_t)s2 * 64];
        uint32_t u3 = h[(size_t)s3 * 64];
        ax += BF16_LO(u0); ay += BF16_HI(u0);
        cx += BF16_LO(u1); cy += BF16_HI(u1);
        ax += BF16_LO(u2); ay += BF16_HI(u2);
        cx += BF16_LO(u3); cy += BF16_HI(u3);
    }
    if (e + 2 <= end) {
        int s0 = es[e], s1 = es[e + 1];
        uint32_t u0 = h[(size_t)s0 * 64];
        uint32_t u1 = h[(size_t)s1 * 64];
        ax += BF16_LO(u0); ay += BF16_HI(u0);
        cx += BF16_LO(u1); cy += BF16_HI(u1);
        e += 2;
    }
    if (e < end) {
        uint32_t u0 = h[(size_t)es[e] * 64];
        ax += BF16_LO(u0); ay += BF16_HI(u0);
    }
    ox += (ax + cx) * w;
    oy += (ay + cy) * w;
}

// --- fused gather layer 0: 3 relations + bias + leakyReLU -> acc0 (fp32) ---
__global__ __launch_bounds__(256)
void gather_l0(const u16* __restrict__ hb, const int* __restrict__ row_start,
               const int* __restrict__ esrc, const float* __restrict__ s_in,
               const float* __restrict__ b, float* __restrict__ out, int N, int E) {
    int node = blockIdx.x * 4 + (threadIdx.x >> 6);
    if (node >= N) return;
    int lane = threadIdx.x & 63;
    float tx = 0.f, ty = 0.f;
#pragma unroll
    for (int r = 0; r < 3; r++) {
        const int* rs = row_start + (size_t)r * (N + 1);
        gather_rel((const uint32_t*)hb + (size_t)r * N * 64 + lane,
                   esrc + (size_t)r * E, rs[node], rs[node + 1],
                   tx, ty, s_in[(size_t)r * N + node]);
    }
    int c0 = lane * 2;
    tx += b[c0] + b[128 + c0] + b[256 + c0];
    ty += b[c0 + 1] + b[128 + c0 + 1] + b[256 + c0 + 1];
    tx = fmaxf(tx, 0.f) + 0.01f * fminf(tx, 0.f);
    ty = fmaxf(ty, 0.f) + 0.01f * fminf(ty, 0.f);
    *(float2*)(out + (size_t)node * 128 + c0) = make_float2(tx, ty);
}

// --- fused gather layer 1: 3 relations + bias -> out_h; + logits -----------
__global__ __launch_bounds__(256)
void gather_l1(const u16* __restrict__ hb, const int* __restrict__ row_start,
               const int* __restrict__ esrc, const float* __restrict__ s_in,
               const float* __restrict__ b, const float* __restrict__ fcW,
               const float* __restrict__ fcb, float* __restrict__ out_h,
               float* __restrict__ out_logits, int N, int E) {
    int node = blockIdx.x * 4 + (threadIdx.x >> 6);
    if (node >= N) return;
    int lane = threadIdx.x & 63;
    float tx = 0.f, ty = 0.f;
#pragma unroll
    for (int r = 0; r < 3; r++) {
        const int* rs = row_start + (size_t)r * (N + 1);
        gather_rel((const uint32_t*)hb + (size_t)r * N * 64 + lane,
                   esrc + (size_t)r * E, rs[node], rs[node + 1],
                   tx, ty, s_in[(size_t)r * N + node]);
    }
    int c0 = lane * 2;
    tx += b[c0] + b[128 + c0] + b[256 + c0];
    ty += b[c0 + 1] + b[128 + c0 + 1] + b[256 + c0 + 1];
    *(float2*)(out_h + (size_t)node * 128 + c0) = make_float2(tx, ty);

    const float* fc0 = fcW + (size_t)c0 * 16;
    float p[16];
#pragma unroll
    for (int j = 0; j < 16; j++) p[j] = tx * fc0[j] + ty * fc0[16 + j];
#pragma unroll
    for (int off = 1; off < 64; off <<= 1) {
#pragma unroll
        for (int j = 0; j < 16; j++) p[j] += __shfl_xor(p[j], off);
    }
    if (lane == 0) {
        float* lp = out_logits + (size_t)node * 16;
        *(float4*)(lp + 0)  = make_float4(p[0] + fcb[0],  p[1] + fcb[1],  p[2] + fcb[2],  p[3] + fcb[3]);
        *(float4*)(lp + 4)  = make_float4(p[4] + fcb[4],  p[5] + fcb[5],  p[6] + fcb[6],  p[7] + fcb[7]);
        *(float4*)(lp + 8)  = make_float4(p[8] + fcb[8],  p[9] + fcb[9],  p[10] + fcb[10], p[11] + fcb[11]);
        *(float4*)(lp + 12) = make_float4(p[12] + fcb[12], p[13] + fcb[13], p[14] + fcb[14], p[15] + fcb[15]);
    }
}

extern "C" void kernel_launch(void* const* d_in, const int* in_sizes, int n_in,
                              void* d_out, int out_size, void* d_ws, size_t ws_size,
                              hipStream_t stream) {
    const float* x   = (const float*)d_in[0];
    const int*   src = (const int*)d_in[1];
    const int*   dst = (const int*)d_in[2];
    const float* W0  = (const float*)d_in[3];
    const float* b0  = (const float*)d_in[4];
    const float* W1  = (const float*)d_in[5];
    const float* b1  = (const float*)d_in[6];
    const float* fcW = (const float*)d_in[7];
    const float* fcb = (const float*)d_in[8];

    const int N = in_sizes[0] / 256;   // 100000
    const int E = in_sizes[1] / 3;     // 600000
    const int nb = (N + SCAN_BLK - 1) / SCAN_BLK;

    float* out_h      = (float*)d_out;
    float* out_logits = out_h + (size_t)N * 128;

    char* p = (char*)d_ws;
    auto alloc = [&](size_t bytes) -> char* {
        char* q = p;
        p += (bytes + 255) & ~(size_t)255;
        return q;
    };
    float* s_out     = (float*)alloc(3 * (size_t)N * 4);
    float* s_in      = (float*)alloc(3 * (size_t)N * 4);
    int*   cnt8      = (int*)alloc(2 * 8 * 3 * (size_t)N * 4);  // out8 then in8
    int*   cnt_out8  = cnt8;
    int*   cnt_in8   = cnt8 + 8 * 3 * (size_t)N;
    int*   cnt_in    = (int*)alloc(3 * (size_t)N * 4);
    int*   row_start = (int*)alloc(3 * (size_t)(N + 1) * 4);
    int*   cursor    = (int*)alloc(3 * (size_t)N * 4);
    int*   bsums     = (int*)alloc(1024 * 4);
    int*   esrc      = (int*)alloc(3 * (size_t)E * 4);
    u16*   w0hi      = (u16*)alloc(3 * 256 * 128 * 2);
    u16*   w0lo      = (u16*)alloc(3 * 256 * 128 * 2);
    u16*   w1hi      = (u16*)alloc(3 * 128 * 128 * 2);
    u16*   w1lo      = (u16*)alloc(3 * 128 * 128 * 2);
    u16*   hb        = (u16*)alloc(3 * (size_t)N * 128 * 2);
    float* acc0      = (float*)alloc((size_t)N * 128 * 4);

    hipMemsetAsync(cnt8, 0, 2 * 8 * 3 * (size_t)N * sizeof(int), stream);

    hist_kernel<<<dim3((E + 255) / 256, 3), 256, 0, stream>>>(src, dst, cnt_out8, cnt_in8, E, N);
    reduce_scales_kernel<<<(3 * N + 255) / 256, 256, 0, stream>>>(
        cnt_out8, cnt_in8, s_out, s_in, cnt_in, 3 * N);

    scan1_kernel<<<dim3(nb, 3), SCAN_T, 0, stream>>>(cnt_in, row_start, bsums, N);
    scan2_kernel<<<1, 1, 0, stream>>>(bsums, row_start, nb, N);
    scan3_kernel<<<dim3(nb, 3), SCAN_T, 0, stream>>>(row_start, bsums, cursor, nb, N);
    bucket_fill_kernel<<<dim3((E + 255) / 256, 3), 256, 0, stream>>>(src, dst, cursor, esrc, E, N);

    prep_w_kernel<<<(3 * 256 * 128 + 3 * 128 * 128 + 255) / 256, 256, 0, stream>>>(
        W0, W1, w0hi, w0lo, w1hi, w1lo);

    int gemm_blocks   = (N + 127) / 128;
    int gather_blocks = (N + 3) / 4;

    // Layer 0: x[N,256] -> hb[r][N,128] bf16 -> acc0[N,128] fp32
    gemm_split_bf16<<<dim3(gemm_blocks, 3), 256, 0, stream>>>(
        x, s_out, w0hi, w0lo, hb, N, 256, N);
    gather_l0<<<gather_blocks, 256, 0, stream>>>(hb, row_start, esrc, s_in, b0, acc0, N, E);

    // Layer 1: acc0[N,128] -> hb[r][N,128] bf16 -> out_h + logits
    gemm_split_bf16<<<dim3(gemm_blocks, 3), 256, 0, stream>>>(
        acc0, s_out, w1hi, w1lo, hb, N, 128, N);
    gather_l1<<<gather_blocks, 256, 0, stream>>>(hb, row_start, esrc, s_in, b1, fcW, fcb,
                                                 out_h, out_logits, N, E);
}